// Round 1
// baseline (288.693 us; speedup 1.0000x reference)
//
#include <hip/hip_runtime.h>
#include <hip/hip_bf16.h>

typedef __attribute__((ext_vector_type(4))) float f32x4;
typedef __attribute__((ext_vector_type(8))) short bf16x8;

#define MFMA(a,b,c) __builtin_amdgcn_mfma_f32_16x16x32_bf16((a),(b),(c),0,0,0)

// Round-to-nearest split of fp32 into hi+lo bf16 (hi = RN(a), lo = RN(a - hi)).
__device__ inline void split_bf16(float a, unsigned short &h, unsigned short &l) {
    unsigned u = __float_as_uint(a);
    unsigned rh = (u + 0x7FFFu + ((u >> 16) & 1u)) & 0xFFFF0000u;
    float hf = __uint_as_float(rh);
    h = (unsigned short)(rh >> 16);
    float lf = a - hf;                      // exact (Sterbenz)
    unsigned u2 = __float_as_uint(lf);
    l = (unsigned short)((u2 + 0x7FFFu + ((u2 >> 16) & 1u)) >> 16);
}

__device__ inline float tanh_fast(float x) {
    // 1 - 2/(e^{2x}+1); exact +-1 saturation for large |x| (exp->inf or 0)
    float e = __expf(2.f * x);
    return 1.f - 2.f * __builtin_amdgcn_rcpf(e + 1.f);
}

// ---------------- prep 1: fold stencils+mix_a into W_eff, pack as B-frags ----
// Pack layout (bf16): [ktile][otile][lane][8], lane = (o&15) + 16*((k>>3)&3), j = k&7
__global__ void prep_weff(const float* __restrict__ mix_a,
                          unsigned short* __restrict__ wph,
                          unsigned short* __restrict__ wpl) {
    int idx = blockIdx.x * 256 + threadIdx.x;     // 128*384 entries
    if (idx >= 128 * 384) return;
    int o = idx / 384;
    int k = idx - o * 384;
    float acc = 0.f;
    if (k < 363) {
        int c = k / 121, rem = k - c * 121;
        int y = rem / 11, x = rem - y * 11;
        const float* ma = mix_a + (size_t)o * 1215 + c * 81;
        auto add = [&](int f, int i, int j, float coef) {
            int n = y - i, m = x - j;
            if (n >= 0 && n < 9 && m >= 0 && m < 9)
                acc += ma[f * 243 + n * 9 + m] * coef;
        };
        add(0, 1, 1, 1.f);
        add(1, 0, 1, -5.f);  add(1, 2, 1, 5.f);
        add(2, 1, 0, -5.f);  add(2, 1, 2, 5.f);
        add(3, 0, 1, 100.f); add(3, 1, 1, -200.f); add(3, 2, 1, 100.f);
        add(4, 1, 0, 100.f); add(4, 1, 1, -200.f); add(4, 1, 2, 100.f);
    }
    unsigned short h, l; split_bf16(acc, h, l);
    int kt = k >> 5, ot = o >> 4;
    int lane = (o & 15) + 16 * ((k >> 3) & 3);
    int jj = k & 7;
    int pidx = ((kt * 8 + ot) * 64 + lane) * 8 + jj;
    wph[pidx] = h; wpl[pidx] = l;
}

// ---------------- prep 2: pack w1/w2/w3 (128x128) and wf (5x128, pad to 16) --
__global__ void prep_layers(const float* __restrict__ w1, const float* __restrict__ w2,
                            const float* __restrict__ w3, const float* __restrict__ wf,
                            unsigned short* __restrict__ wlh, unsigned short* __restrict__ wll,
                            unsigned short* __restrict__ wfh, unsigned short* __restrict__ wfl) {
    int idx = blockIdx.x * 256 + threadIdx.x;     // 3*16384 + 2048
    if (idx < 3 * 16384) {
        int layer = idx >> 14; int rem = idx & 16383;
        int o = rem >> 7, k = rem & 127;
        const float* w = (layer == 0) ? w1 : ((layer == 1) ? w2 : w3);
        float v = w[o * 128 + k];
        unsigned short h, l; split_bf16(v, h, l);
        int kt = k >> 5, ot = o >> 4;
        int lane = (o & 15) + 16 * ((k >> 3) & 3);
        int pidx = layer * 16384 + ((kt * 8 + ot) * 64 + lane) * 8 + (k & 7);
        wlh[pidx] = h; wll[pidx] = l;
    } else if (idx < 3 * 16384 + 2048) {
        int rem = idx - 3 * 16384;
        int o = rem >> 7, k = rem & 127;
        float v = (o < 5) ? wf[o * 128 + k] : 0.f;
        unsigned short h, l; split_bf16(v, h, l);
        int kt = k >> 5;
        int lane = (o & 15) + 16 * ((k >> 3) & 3);
        int pidx = (kt * 64 + lane) * 8 + (k & 7);
        wfh[pidx] = h; wfl[pidx] = l;
    }
}

// ---------------- fused main: 16 samples per wave, barrier-free -------------
__global__ __launch_bounds__(256, 3)
void fused_main(const float* __restrict__ data,
                const float* __restrict__ mix_b,
                const float* __restrict__ b1v,
                const float* __restrict__ b2v,
                const float* __restrict__ b3v,
                const float* __restrict__ bfv,
                const unsigned short* __restrict__ wp1h,
                const unsigned short* __restrict__ wp1l,
                const unsigned short* __restrict__ wlh,
                const unsigned short* __restrict__ wll,
                const unsigned short* __restrict__ wfh,
                const unsigned short* __restrict__ wfl,
                float* __restrict__ out, int Btot) {
    // per-wave LDS; row pads (+8 bf16 = 16B) give 4-bank row rotation -> 2-way (free)
    __shared__ __align__(16) unsigned short AsH[4][16][72];
    __shared__ __align__(16) unsigned short AsL[4][16][72];
    __shared__ __align__(16) unsigned short XsH[4][16][136];
    __shared__ __align__(16) unsigned short XsL[4][16][136];

    const int wave = threadIdx.x >> 6;
    const int lane = threadIdx.x & 63;
    const int s0 = (blockIdx.x * 4 + wave) * 16;
    if (s0 >= Btot) return;
    const int col = lane & 15;   // MFMA n / D col
    const int kg  = lane >> 4;   // k-group 0..3

    f32x4 acc[8];
    #pragma unroll
    for (int ot = 0; ot < 8; ++ot) {
        float b = mix_b[col + 16 * ot];
        acc[ot] = (f32x4){b, b, b, b};
    }

    // ---- stage 1: mixed = data @ W_eff^T, K padded 363->384 ----
    const int r  = lane >> 2;         // staging row 0..15
    const int cb = (lane & 3) * 16;   // staging col base
    const float* dp = data + (size_t)(s0 + r) * 363;
    for (int kc = 0; kc < 384; kc += 64) {
        asm volatile("s_waitcnt lgkmcnt(0)" ::: "memory"); // prev-chunk reads done
        #pragma unroll
        for (int t = 0; t < 16; t += 2) {
            int c0 = kc + cb + t;
            float v0 = (c0     < 363) ? dp[c0]     : 0.f;
            float v1 = (c0 + 1 < 363) ? dp[c0 + 1] : 0.f;
            unsigned short h0, l0, h1, l1;
            split_bf16(v0, h0, l0); split_bf16(v1, h1, l1);
            *(unsigned int*)&AsH[wave][r][cb + t] = (unsigned)h0 | ((unsigned)h1 << 16);
            *(unsigned int*)&AsL[wave][r][cb + t] = (unsigned)l0 | ((unsigned)l1 << 16);
        }
        asm volatile("s_waitcnt lgkmcnt(0)" ::: "memory"); // writes visible to reads
        #pragma unroll
        for (int kt = 0; kt < 2; ++kt) {
            int ko = kt * 32 + kg * 8;
            bf16x8 ah = *(const bf16x8*)&AsH[wave][col][ko];
            bf16x8 al = *(const bf16x8*)&AsL[wave][col][ko];
            int ktg = (kc >> 5) + kt;
            const unsigned short* ph = wp1h + ((size_t)(ktg * 8) * 64 + lane) * 8;
            const unsigned short* pl = wp1l + ((size_t)(ktg * 8) * 64 + lane) * 8;
            #pragma unroll
            for (int ot = 0; ot < 8; ++ot) {
                bf16x8 bh = *(const bf16x8*)(ph + (size_t)ot * 512);
                bf16x8 bl = *(const bf16x8*)(pl + (size_t)ot * 512);
                acc[ot] = MFMA(ah, bh, acc[ot]);
                acc[ot] = MFMA(ah, bl, acc[ot]);
                acc[ot] = MFMA(al, bh, acc[ot]);
            }
        }
    }

    // mixed -> tanh -> Xs (hi/lo)
    #pragma unroll
    for (int ot = 0; ot < 8; ++ot) {
        #pragma unroll
        for (int j = 0; j < 4; ++j) {
            float x = tanh_fast(acc[ot][j]);
            unsigned short h, l; split_bf16(x, h, l);
            XsH[wave][kg * 4 + j][col + 16 * ot] = h;
            XsL[wave][kg * 4 + j][col + 16 * ot] = l;
        }
    }

    // ---- 3 hidden layers, K=128 ----
    const float* biases[3] = {b1v, b2v, b3v};
    #pragma unroll
    for (int layer = 0; layer < 3; ++layer) {
        asm volatile("s_waitcnt lgkmcnt(0)" ::: "memory"); // X writes visible
        const float* bb = biases[layer];
        f32x4 nacc[8];
        #pragma unroll
        for (int ot = 0; ot < 8; ++ot) {
            float b = bb[col + 16 * ot];
            nacc[ot] = (f32x4){b, b, b, b};
        }
        const unsigned short* ph0 = wlh + (size_t)layer * 16384;
        const unsigned short* pl0 = wll + (size_t)layer * 16384;
        #pragma unroll
        for (int kt = 0; kt < 4; ++kt) {
            int ko = kt * 32 + kg * 8;
            bf16x8 ah = *(const bf16x8*)&XsH[wave][col][ko];
            bf16x8 al = *(const bf16x8*)&XsL[wave][col][ko];
            #pragma unroll
            for (int ot = 0; ot < 8; ++ot) {
                bf16x8 bh = *(const bf16x8*)(ph0 + ((size_t)(kt * 8 + ot) * 64 + lane) * 8);
                bf16x8 bl = *(const bf16x8*)(pl0 + ((size_t)(kt * 8 + ot) * 64 + lane) * 8);
                nacc[ot] = MFMA(ah, bh, nacc[ot]);
                nacc[ot] = MFMA(ah, bl, nacc[ot]);
                nacc[ot] = MFMA(al, bh, nacc[ot]);
            }
        }
        asm volatile("s_waitcnt lgkmcnt(0)" ::: "memory"); // layer reads done before overwrite
        #pragma unroll
        for (int ot = 0; ot < 8; ++ot) {
            #pragma unroll
            for (int j = 0; j < 4; ++j) {
                float x = tanh_fast(nacc[ot][j]);
                unsigned short h, l; split_bf16(x, h, l);
                XsH[wave][kg * 4 + j][col + 16 * ot] = h;
                XsL[wave][kg * 4 + j][col + 16 * ot] = l;
            }
        }
    }

    // ---- final layer 128 -> 5 (N padded to 16) ----
    asm volatile("s_waitcnt lgkmcnt(0)" ::: "memory");
    float fb = (col < 5) ? bfv[col] : 0.f;
    f32x4 facc = (f32x4){fb, fb, fb, fb};
    #pragma unroll
    for (int kt = 0; kt < 4; ++kt) {
        int ko = kt * 32 + kg * 8;
        bf16x8 ah = *(const bf16x8*)&XsH[wave][col][ko];
        bf16x8 al = *(const bf16x8*)&XsL[wave][col][ko];
        bf16x8 bh = *(const bf16x8*)(wfh + ((size_t)kt * 64 + lane) * 8);
        bf16x8 bl = *(const bf16x8*)(wfl + ((size_t)kt * 64 + lane) * 8);
        facc = MFMA(ah, bh, facc);
        facc = MFMA(ah, bl, facc);
        facc = MFMA(al, bh, facc);
    }
    if (col < 5) {
        #pragma unroll
        for (int j = 0; j < 4; ++j) {
            int s = s0 + kg * 4 + j;
            if (s < Btot) out[(size_t)s * 5 + col] = facc[j];
        }
    }
}

extern "C" void kernel_launch(void* const* d_in, const int* in_sizes, int n_in,
                              void* d_out, int out_size, void* d_ws, size_t ws_size,
                              hipStream_t stream) {
    const float* data  = (const float*)d_in[0];
    const float* mix_a = (const float*)d_in[1];
    const float* mix_b = (const float*)d_in[2];
    const float* w1    = (const float*)d_in[3];
    const float* b1    = (const float*)d_in[4];
    const float* w2    = (const float*)d_in[5];
    const float* b2    = (const float*)d_in[6];
    const float* w3    = (const float*)d_in[7];
    const float* b3    = (const float*)d_in[8];
    const float* wf    = (const float*)d_in[9];
    const float* bf    = (const float*)d_in[10];
    float* out = (float*)d_out;
    int Btot = in_sizes[0] / 363;

    if (ws_size < 401408) return;   // need 401,408 B of scratch
    unsigned short* wp1h = (unsigned short*)d_ws;      // 49152 ushorts
    unsigned short* wp1l = wp1h + 49152;
    unsigned short* wlh  = wp1l + 49152;               // 3*16384
    unsigned short* wll  = wlh + 49152;
    unsigned short* wfh  = wll + 49152;                // 2048
    unsigned short* wfl  = wfh + 2048;

    prep_weff<<<192, 256, 0, stream>>>(mix_a, wp1h, wp1l);
    prep_layers<<<200, 256, 0, stream>>>(w1, w2, w3, wf, wlh, wll, wfh, wfl);
    int blocks = (Btot + 63) / 64;
    fused_main<<<blocks, 256, 0, stream>>>(data, mix_b, b1, b2, b3, bf,
                                           wp1h, wp1l, wlh, wll, wfh, wfl, out, Btot);
}

// Round 3
// 219.644 us; speedup vs baseline: 1.3144x; 1.3144x over previous
//
#include <hip/hip_runtime.h>
#include <hip/hip_bf16.h>

typedef __attribute__((ext_vector_type(4))) float f32x4;
typedef __attribute__((ext_vector_type(8))) short bf16x8;

#define MFMA(a,b,c) __builtin_amdgcn_mfma_f32_16x16x32_bf16((a),(b),(c),0,0,0)

// Round-to-nearest split of fp32 into hi+lo bf16 (hi = RN(a), lo = RN(a - hi)).
__device__ inline void split_bf16(float a, unsigned short &h, unsigned short &l) {
    unsigned u = __float_as_uint(a);
    unsigned rh = (u + 0x7FFFu + ((u >> 16) & 1u)) & 0xFFFF0000u;
    float hf = __uint_as_float(rh);
    h = (unsigned short)(rh >> 16);
    float lf = a - hf;                      // exact (Sterbenz)
    unsigned u2 = __float_as_uint(lf);
    l = (unsigned short)((u2 + 0x7FFFu + ((u2 >> 16) & 1u)) >> 16);
}

__device__ inline float tanh_fast(float x) {
    float e = __expf(2.f * x);
    return 1.f - 2.f * __builtin_amdgcn_rcpf(e + 1.f);
}

// ---------------- prep 1: fold stencils+mix_a into W_eff, pack as B-frags ----
// Pack layout (bf16): [ktile][otile][lane][8], lane = (o&15) + 16*((k>>3)&3), j = k&7
__global__ void prep_weff(const float* __restrict__ mix_a,
                          unsigned short* __restrict__ wph,
                          unsigned short* __restrict__ wpl) {
    int idx = blockIdx.x * 256 + threadIdx.x;     // 128*384 entries
    if (idx >= 128 * 384) return;
    int o = idx / 384;
    int k = idx - o * 384;
    float acc = 0.f;
    if (k < 363) {
        int c = k / 121, rem = k - c * 121;
        int y = rem / 11, x = rem - y * 11;
        const float* ma = mix_a + (size_t)o * 1215 + c * 81;
        auto add = [&](int f, int i, int j, float coef) {
            int n = y - i, m = x - j;
            if (n >= 0 && n < 9 && m >= 0 && m < 9)
                acc += ma[f * 243 + n * 9 + m] * coef;
        };
        add(0, 1, 1, 1.f);
        add(1, 0, 1, -5.f);  add(1, 2, 1, 5.f);
        add(2, 1, 0, -5.f);  add(2, 1, 2, 5.f);
        add(3, 0, 1, 100.f); add(3, 1, 1, -200.f); add(3, 2, 1, 100.f);
        add(4, 1, 0, 100.f); add(4, 1, 1, -200.f); add(4, 1, 2, 100.f);
    }
    unsigned short h, l; split_bf16(acc, h, l);
    int kt = k >> 5, ot = o >> 4;
    int lane = (o & 15) + 16 * ((k >> 3) & 3);
    int jj = k & 7;
    int pidx = ((kt * 8 + ot) * 64 + lane) * 8 + jj;
    wph[pidx] = h; wpl[pidx] = l;
}

// ---------------- prep 2: pack w1/w2/w3 (128x128) and wf (5x128, pad to 16) --
__global__ void prep_layers(const float* __restrict__ w1, const float* __restrict__ w2,
                            const float* __restrict__ w3, const float* __restrict__ wf,
                            unsigned short* __restrict__ wlh, unsigned short* __restrict__ wll,
                            unsigned short* __restrict__ wfh, unsigned short* __restrict__ wfl) {
    int idx = blockIdx.x * 256 + threadIdx.x;     // 3*16384 + 2048
    if (idx < 3 * 16384) {
        int layer = idx >> 14; int rem = idx & 16383;
        int o = rem >> 7, k = rem & 127;
        const float* w = (layer == 0) ? w1 : ((layer == 1) ? w2 : w3);
        float v = w[o * 128 + k];
        unsigned short h, l; split_bf16(v, h, l);
        int kt = k >> 5, ot = o >> 4;
        int lane = (o & 15) + 16 * ((k >> 3) & 3);
        int pidx = layer * 16384 + ((kt * 8 + ot) * 64 + lane) * 8 + (k & 7);
        wlh[pidx] = h; wll[pidx] = l;
    } else if (idx < 3 * 16384 + 2048) {
        int rem = idx - 3 * 16384;
        int o = rem >> 7, k = rem & 127;
        float v = (o < 5) ? wf[o * 128 + k] : 0.f;
        unsigned short h, l; split_bf16(v, h, l);
        int kt = k >> 5;
        int lane = (o & 15) + 16 * ((k >> 3) & 3);
        int pidx = (kt * 64 + lane) * 8 + (k & 7);
        wfh[pidx] = h; wfl[pidx] = l;
    }
}

// ---------------- fused main: 32 samples per wave (2 M-tiles), barrier-free --
// A-operand: global -> registers directly in fragment order (no LDS staging).
// B fragments loaded once per (kt,ot), reused by both M-tiles.
__global__ __launch_bounds__(256, 2)
void fused_main(const float* __restrict__ data,
                const float* __restrict__ mix_b,
                const float* __restrict__ b1v,
                const float* __restrict__ b2v,
                const float* __restrict__ b3v,
                const float* __restrict__ bfv,
                const unsigned short* __restrict__ wp1h,
                const unsigned short* __restrict__ wp1l,
                const unsigned short* __restrict__ wlh,
                const unsigned short* __restrict__ wll,
                const unsigned short* __restrict__ wfh,
                const unsigned short* __restrict__ wfl,
                float* __restrict__ out, int Btot) {
    // per-wave, per-tile X transpose buffers; stride 136 elems = 272 B (16B-mult)
    __shared__ __align__(16) unsigned short XsH[4][2][16][136];
    __shared__ __align__(16) unsigned short XsL[4][2][16][136];

    const int wave = threadIdx.x >> 6;
    const int lane = threadIdx.x & 63;
    const int s0 = (blockIdx.x * 4 + wave) * 32;
    if (s0 >= Btot) return;
    const int col = lane & 15;   // MFMA row (sample within tile) for A, col for C/D
    const int kg  = lane >> 4;   // k-group 0..3

    // NOTE: k-offset (kg*8) is applied in the INDEX below, not here.
    // Round-2 bug was adding it in both places (double-counted for kg!=0).
    const float* ap0 = data + (size_t)(s0 + col) * 363;
    const float* ap1 = ap0 + (size_t)16 * 363;

    f32x4 acc[2][8];
    #pragma unroll
    for (int ot = 0; ot < 8; ++ot) {
        float b = mix_b[col + 16 * ot];
        acc[0][ot] = (f32x4){b, b, b, b};
        acc[1][ot] = (f32x4){b, b, b, b};
    }

    // ---- stage 1: mixed = data @ W_eff^T, K padded 363->384, reg dbuf ----
    float abuf[2][2][16];   // [ping-pong][tile][2kt*8]
    #pragma unroll
    for (int kt = 0; kt < 2; ++kt)
        #pragma unroll
        for (int j = 0; j < 8; ++j) {
            int k = kt * 32 + kg * 8 + j;   // <= 63, always valid
            abuf[0][0][kt * 8 + j] = ap0[k];
            abuf[0][1][kt * 8 + j] = ap1[k];
        }

    #pragma unroll
    for (int c = 0; c < 6; ++c) {
        const int kc = c * 64;
        const int cur = c & 1, nxt = cur ^ 1;
        if (c < 5) {   // prefetch next chunk (compile-time predicates fold for c<4)
            #pragma unroll
            for (int kt = 0; kt < 2; ++kt)
                #pragma unroll
                for (int j = 0; j < 8; ++j) {
                    int k = kc + 64 + kt * 32 + kg * 8 + j;
                    bool ok = (k < 363);
                    abuf[nxt][0][kt * 8 + j] = ok ? ap0[k] : 0.f;
                    abuf[nxt][1][kt * 8 + j] = ok ? ap1[k] : 0.f;
                }
        }
        #pragma unroll
        for (int kt = 0; kt < 2; ++kt) {
            bf16x8 ah[2], al[2];
            #pragma unroll
            for (int t = 0; t < 2; ++t)
                #pragma unroll
                for (int j = 0; j < 8; ++j) {
                    unsigned short h, l;
                    split_bf16(abuf[cur][t][kt * 8 + j], h, l);
                    ah[t][j] = (short)h; al[t][j] = (short)l;
                }
            const int ktg = kc / 32 + kt;
            const unsigned short* ph = wp1h + ((size_t)(ktg * 8) * 64 + (size_t)lane) * 8;
            const unsigned short* pl = wp1l + ((size_t)(ktg * 8) * 64 + (size_t)lane) * 8;
            #pragma unroll
            for (int ot = 0; ot < 8; ++ot) {
                bf16x8 bh = *(const bf16x8*)(ph + (size_t)ot * 512);
                bf16x8 bl = *(const bf16x8*)(pl + (size_t)ot * 512);
                acc[0][ot] = MFMA(ah[0], bh, acc[0][ot]);
                acc[0][ot] = MFMA(ah[0], bl, acc[0][ot]);
                acc[0][ot] = MFMA(al[0], bh, acc[0][ot]);
                acc[1][ot] = MFMA(ah[1], bh, acc[1][ot]);
                acc[1][ot] = MFMA(ah[1], bl, acc[1][ot]);
                acc[1][ot] = MFMA(al[1], bh, acc[1][ot]);
            }
        }
    }

    // mixed -> tanh -> Xs (hi/lo)
    #pragma unroll
    for (int t = 0; t < 2; ++t)
        #pragma unroll
        for (int ot = 0; ot < 8; ++ot)
            #pragma unroll
            for (int j = 0; j < 4; ++j) {
                float x = tanh_fast(acc[t][ot][j]);
                unsigned short h, l; split_bf16(x, h, l);
                XsH[wave][t][kg * 4 + j][col + 16 * ot] = h;
                XsL[wave][t][kg * 4 + j][col + 16 * ot] = l;
            }

    // ---- 3 hidden layers, K=128 ----
    const float* biases[3] = {b1v, b2v, b3v};
    #pragma unroll
    for (int layer = 0; layer < 3; ++layer) {
        asm volatile("s_waitcnt lgkmcnt(0)" ::: "memory"); // X writes visible (in-wave)
        const float* bb = biases[layer];
        f32x4 nacc[2][8];
        #pragma unroll
        for (int ot = 0; ot < 8; ++ot) {
            float b = bb[col + 16 * ot];
            nacc[0][ot] = (f32x4){b, b, b, b};
            nacc[1][ot] = (f32x4){b, b, b, b};
        }
        const unsigned short* ph0 = wlh + (size_t)layer * 16384;
        const unsigned short* pl0 = wll + (size_t)layer * 16384;
        #pragma unroll
        for (int kt = 0; kt < 4; ++kt) {
            bf16x8 xh[2], xl[2];
            #pragma unroll
            for (int t = 0; t < 2; ++t) {
                xh[t] = *(const bf16x8*)&XsH[wave][t][col][kt * 32 + kg * 8];
                xl[t] = *(const bf16x8*)&XsL[wave][t][col][kt * 32 + kg * 8];
            }
            #pragma unroll
            for (int ot = 0; ot < 8; ++ot) {
                bf16x8 bh = *(const bf16x8*)(ph0 + ((size_t)(kt * 8 + ot) * 64 + lane) * 8);
                bf16x8 bl = *(const bf16x8*)(pl0 + ((size_t)(kt * 8 + ot) * 64 + lane) * 8);
                nacc[0][ot] = MFMA(xh[0], bh, nacc[0][ot]);
                nacc[0][ot] = MFMA(xh[0], bl, nacc[0][ot]);
                nacc[0][ot] = MFMA(xl[0], bh, nacc[0][ot]);
                nacc[1][ot] = MFMA(xh[1], bh, nacc[1][ot]);
                nacc[1][ot] = MFMA(xh[1], bl, nacc[1][ot]);
                nacc[1][ot] = MFMA(xl[1], bh, nacc[1][ot]);
            }
        }
        asm volatile("s_waitcnt lgkmcnt(0)" ::: "memory"); // reads done before overwrite
        #pragma unroll
        for (int t = 0; t < 2; ++t)
            #pragma unroll
            for (int ot = 0; ot < 8; ++ot)
                #pragma unroll
                for (int j = 0; j < 4; ++j) {
                    float x = tanh_fast(nacc[t][ot][j]);
                    unsigned short h, l; split_bf16(x, h, l);
                    XsH[wave][t][kg * 4 + j][col + 16 * ot] = h;
                    XsL[wave][t][kg * 4 + j][col + 16 * ot] = l;
                }
    }

    // ---- final layer 128 -> 5 (N padded to 16) ----
    asm volatile("s_waitcnt lgkmcnt(0)" ::: "memory");
    float fb = (col < 5) ? bfv[col] : 0.f;
    f32x4 facc[2];
    facc[0] = (f32x4){fb, fb, fb, fb};
    facc[1] = (f32x4){fb, fb, fb, fb};
    #pragma unroll
    for (int kt = 0; kt < 4; ++kt) {
        bf16x8 bh = *(const bf16x8*)(wfh + ((size_t)kt * 64 + lane) * 8);
        bf16x8 bl = *(const bf16x8*)(wfl + ((size_t)kt * 64 + lane) * 8);
        #pragma unroll
        for (int t = 0; t < 2; ++t) {
            bf16x8 xh = *(const bf16x8*)&XsH[wave][t][col][kt * 32 + kg * 8];
            bf16x8 xl = *(const bf16x8*)&XsL[wave][t][col][kt * 32 + kg * 8];
            facc[t] = MFMA(xh, bh, facc[t]);
            facc[t] = MFMA(xh, bl, facc[t]);
            facc[t] = MFMA(xl, bh, facc[t]);
        }
    }
    if (col < 5) {
        #pragma unroll
        for (int t = 0; t < 2; ++t)
            #pragma unroll
            for (int j = 0; j < 4; ++j) {
                int s = s0 + 16 * t + kg * 4 + j;
                if (s < Btot) out[(size_t)s * 5 + col] = facc[t][j];
            }
    }
}

extern "C" void kernel_launch(void* const* d_in, const int* in_sizes, int n_in,
                              void* d_out, int out_size, void* d_ws, size_t ws_size,
                              hipStream_t stream) {
    const float* data  = (const float*)d_in[0];
    const float* mix_a = (const float*)d_in[1];
    const float* mix_b = (const float*)d_in[2];
    const float* w1    = (const float*)d_in[3];
    const float* b1    = (const float*)d_in[4];
    const float* w2    = (const float*)d_in[5];
    const float* b2    = (const float*)d_in[6];
    const float* w3    = (const float*)d_in[7];
    const float* b3    = (const float*)d_in[8];
    const float* wf    = (const float*)d_in[9];
    const float* bf    = (const float*)d_in[10];
    float* out = (float*)d_out;
    int Btot = in_sizes[0] / 363;

    if (ws_size < 401408) return;   // need 401,408 B of scratch
    unsigned short* wp1h = (unsigned short*)d_ws;      // 49152 ushorts
    unsigned short* wp1l = wp1h + 49152;
    unsigned short* wlh  = wp1l + 49152;               // 3*16384
    unsigned short* wll  = wlh + 49152;
    unsigned short* wfh  = wll + 49152;                // 2048
    unsigned short* wfl  = wfh + 2048;

    prep_weff<<<192, 256, 0, stream>>>(mix_a, wp1h, wp1l);
    prep_layers<<<200, 256, 0, stream>>>(w1, w2, w3, wf, wlh, wll, wfh, wfl);
    int blocks = (Btot + 127) / 128;
    fused_main<<<blocks, 256, 0, stream>>>(data, mix_b, b1, b2, b3, bf,
                                           wp1h, wp1l, wlh, wll, wfh, wfl, out, Btot);
}

// Round 4
// 206.998 us; speedup vs baseline: 1.3947x; 1.0611x over previous
//
#include <hip/hip_runtime.h>
#include <hip/hip_bf16.h>

typedef __attribute__((ext_vector_type(4))) float f32x4;
typedef __attribute__((ext_vector_type(8))) short bf16x8;

#define MFMA(a,b,c) __builtin_amdgcn_mfma_f32_16x16x32_bf16((a),(b),(c),0,0,0)

// Round-to-nearest split of fp32 into hi+lo bf16 (hi = RN(a), lo = RN(a - hi)).
__device__ inline void split_bf16(float a, unsigned short &h, unsigned short &l) {
    unsigned u = __float_as_uint(a);
    unsigned rh = (u + 0x7FFFu + ((u >> 16) & 1u)) & 0xFFFF0000u;
    float hf = __uint_as_float(rh);
    h = (unsigned short)(rh >> 16);
    float lf = a - hf;                      // exact (Sterbenz)
    unsigned u2 = __float_as_uint(lf);
    l = (unsigned short)((u2 + 0x7FFFu + ((u2 >> 16) & 1u)) >> 16);
}

__device__ inline float tanh_fast(float x) {
    float e = __expf(2.f * x);
    return 1.f - 2.f * __builtin_amdgcn_rcpf(e + 1.f);
}

__device__ inline bf16x8 ldb(const unsigned short* p) { return *(const bf16x8*)p; }
// 16B load safe at 4B alignment (memcpy lets the backend pick legal width)
__device__ inline f32x4 ld4u(const float* p) { f32x4 v; __builtin_memcpy(&v, p, 16); return v; }

// ---------------- merged prep: W_eff fold + layer packs --------------------
// Pack layout (bf16): [ktile][otile][lane][8], lane = (o&15) + 16*((k>>3)&3), j = k&7
__global__ void prep_all(const float* __restrict__ mix_a,
                         const float* __restrict__ w1, const float* __restrict__ w2,
                         const float* __restrict__ w3, const float* __restrict__ wf,
                         unsigned short* __restrict__ wph, unsigned short* __restrict__ wpl,
                         unsigned short* __restrict__ wlh, unsigned short* __restrict__ wll,
                         unsigned short* __restrict__ wfh, unsigned short* __restrict__ wfl) {
    int idx = blockIdx.x * 256 + threadIdx.x;
    if (idx < 128 * 384) {
        int o = idx / 384;
        int k = idx - o * 384;
        float acc = 0.f;
        if (k < 363) {
            int c = k / 121, rem = k - c * 121;
            int y = rem / 11, x = rem - y * 11;
            const float* ma = mix_a + (size_t)o * 1215 + c * 81;
            auto add = [&](int f, int i, int j, float coef) {
                int n = y - i, m = x - j;
                if (n >= 0 && n < 9 && m >= 0 && m < 9)
                    acc += ma[f * 243 + n * 9 + m] * coef;
            };
            add(0, 1, 1, 1.f);
            add(1, 0, 1, -5.f);  add(1, 2, 1, 5.f);
            add(2, 1, 0, -5.f);  add(2, 1, 2, 5.f);
            add(3, 0, 1, 100.f); add(3, 1, 1, -200.f); add(3, 2, 1, 100.f);
            add(4, 1, 0, 100.f); add(4, 1, 1, -200.f); add(4, 1, 2, 100.f);
        }
        unsigned short h, l; split_bf16(acc, h, l);
        int kt = k >> 5, ot = o >> 4;
        int lane = (o & 15) + 16 * ((k >> 3) & 3);
        int pidx = ((kt * 8 + ot) * 64 + lane) * 8 + (k & 7);
        wph[pidx] = h; wpl[pidx] = l;
        return;
    }
    idx -= 128 * 384;
    if (idx < 3 * 16384) {
        int layer = idx >> 14; int rem = idx & 16383;
        int o = rem >> 7, k = rem & 127;
        const float* w = (layer == 0) ? w1 : ((layer == 1) ? w2 : w3);
        float v = w[o * 128 + k];
        unsigned short h, l; split_bf16(v, h, l);
        int kt = k >> 5, ot = o >> 4;
        int lane = (o & 15) + 16 * ((k >> 3) & 3);
        int pidx = layer * 16384 + ((kt * 8 + ot) * 64 + lane) * 8 + (k & 7);
        wlh[pidx] = h; wll[pidx] = l;
    } else if (idx < 3 * 16384 + 2048) {
        int rem = idx - 3 * 16384;
        int o = rem >> 7, k = rem & 127;
        float v = (o < 5) ? wf[o * 128 + k] : 0.f;
        unsigned short h, l; split_bf16(v, h, l);
        int kt = k >> 5;
        int lane = (o & 15) + 16 * ((k >> 3) & 3);
        int pidx = (kt * 64 + lane) * 8 + (k & 7);
        wfh[pidx] = h; wfl[pidx] = l;
    }
}

// ---------------- fused main: 32 samples/wave, reg-pipelined B ------------
__global__ __launch_bounds__(256, 2)
void fused_main(const float* __restrict__ data,
                const float* __restrict__ mix_b,
                const float* __restrict__ b1v,
                const float* __restrict__ b2v,
                const float* __restrict__ b3v,
                const float* __restrict__ bfv,
                const unsigned short* __restrict__ wp1h,
                const unsigned short* __restrict__ wp1l,
                const unsigned short* __restrict__ wlh,
                const unsigned short* __restrict__ wll,
                const unsigned short* __restrict__ wfh,
                const unsigned short* __restrict__ wfl,
                float* __restrict__ out, int Btot) {
    __shared__ __align__(16) unsigned short XsH[4][2][16][136];
    __shared__ __align__(16) unsigned short XsL[4][2][16][136];

    const int wave = threadIdx.x >> 6;
    const int lane = threadIdx.x & 63;
    const int s0 = (blockIdx.x * 4 + wave) * 32;
    if (s0 >= Btot) return;          // never taken at B=65536 (grid exact); no barriers used
    const int col = lane & 15;
    const int kg  = lane >> 4;

    const float* arow0 = data + (size_t)(s0 + col) * 363;
    const float* arow1 = arow0 + (size_t)16 * 363;

    f32x4 acc[2][8];
    #pragma unroll
    for (int ot = 0; ot < 8; ++ot) {
        float b = mix_b[col + 16 * ot];
        acc[0][ot] = (f32x4){b, b, b, b};
        acc[1][ot] = (f32x4){b, b, b, b};
    }

    // ---- stage 1: mixed = data @ W_eff^T, 12 k-steps of 32 ----
    bf16x8 bh[2][8], bl[8];
    f32x4 a4[2][2][2];               // [pp][tile][half-of-8-floats]
    a4[0][0][0] = ld4u(arow0 + kg * 8);     a4[0][0][1] = ld4u(arow0 + kg * 8 + 4);
    a4[0][1][0] = ld4u(arow1 + kg * 8);     a4[0][1][1] = ld4u(arow1 + kg * 8 + 4);
    #pragma unroll
    for (int ot = 0; ot < 8; ++ot)
        bh[0][ot] = ldb(wp1h + ((size_t)ot * 64 + lane) * 8);

    #pragma unroll
    for (int ktg = 0; ktg < 12; ++ktg) {
        const int p = ktg & 1;
        // bl for current step (used in pass 3, ~32 MFMAs later)
        #pragma unroll
        for (int ot = 0; ot < 8; ++ot)
            bl[ot] = ldb(wp1l + (((size_t)(ktg * 8 + ot)) * 64 + lane) * 8);
        // prefetch next step's bh
        if (ktg < 11) {
            #pragma unroll
            for (int ot = 0; ot < 8; ++ot)
                bh[p ^ 1][ot] = ldb(wp1h + (((size_t)((ktg + 1) * 8 + ot)) * 64 + lane) * 8);
        }
        // prefetch next step's A
        if (ktg < 10) {
            const int kb = (ktg + 1) * 32 + kg * 8;
            a4[p ^ 1][0][0] = ld4u(arow0 + kb); a4[p ^ 1][0][1] = ld4u(arow0 + kb + 4);
            a4[p ^ 1][1][0] = ld4u(arow1 + kb); a4[p ^ 1][1][1] = ld4u(arow1 + kb + 4);
        } else if (ktg == 10) {
            // last k-step: masked scalar (k>=363 invalid; don't run past buffer end)
            #pragma unroll
            for (int i = 0; i < 2; ++i)
                #pragma unroll
                for (int j = 0; j < 4; ++j) {
                    int k = 352 + kg * 8 + i * 4 + j;
                    bool ok = (k < 363);
                    a4[p ^ 1][0][i][j] = ok ? arow0[k] : 0.f;
                    a4[p ^ 1][1][i][j] = ok ? arow1[k] : 0.f;
                }
        }
        // split current A into hi/lo fragments
        bf16x8 ah[2], al[2];
        #pragma unroll
        for (int t = 0; t < 2; ++t)
            #pragma unroll
            for (int i = 0; i < 2; ++i)
                #pragma unroll
                for (int j = 0; j < 4; ++j) {
                    unsigned short hh, ll;
                    split_bf16(a4[p][t][i][j], hh, ll);
                    ah[t][i * 4 + j] = (short)hh;
                    al[t][i * 4 + j] = (short)ll;
                }
        #pragma unroll
        for (int ot = 0; ot < 8; ++ot) {
            acc[0][ot] = MFMA(ah[0], bh[p][ot], acc[0][ot]);
            acc[1][ot] = MFMA(ah[1], bh[p][ot], acc[1][ot]);
        }
        #pragma unroll
        for (int ot = 0; ot < 8; ++ot) {
            acc[0][ot] = MFMA(al[0], bh[p][ot], acc[0][ot]);
            acc[1][ot] = MFMA(al[1], bh[p][ot], acc[1][ot]);
        }
        #pragma unroll
        for (int ot = 0; ot < 8; ++ot) {
            acc[0][ot] = MFMA(ah[0], bl[ot], acc[0][ot]);
            acc[1][ot] = MFMA(ah[1], bl[ot], acc[1][ot]);
        }
    }

    // mixed -> tanh -> Xs (hi/lo)
    #pragma unroll
    for (int t = 0; t < 2; ++t)
        #pragma unroll
        for (int ot = 0; ot < 8; ++ot)
            #pragma unroll
            for (int j = 0; j < 4; ++j) {
                float x = tanh_fast(acc[t][ot][j]);
                unsigned short h, l; split_bf16(x, h, l);
                XsH[wave][t][kg * 4 + j][col + 16 * ot] = h;
                XsL[wave][t][kg * 4 + j][col + 16 * ot] = l;
            }

    // ---- 3 hidden layers, flattened 12 k-steps with bh prefetch chain ----
    const float* biases[3] = {b1v, b2v, b3v};
    bf16x8 lbh[2][8], lbl[8];
    asm volatile("s_waitcnt lgkmcnt(0)" ::: "memory");   // X writes visible
    #pragma unroll
    for (int ot = 0; ot < 8; ++ot)                        // preload L0,kt0 bh
        lbh[0][ot] = ldb(wlh + ((size_t)ot * 64 + lane) * 8);

    #pragma unroll
    for (int layer = 0; layer < 3; ++layer) {
        const float* bb = biases[layer];
        f32x4 nacc[2][8];
        #pragma unroll
        for (int ot = 0; ot < 8; ++ot) {
            float b = bb[col + 16 * ot];
            nacc[0][ot] = (f32x4){b, b, b, b};
            nacc[1][ot] = (f32x4){b, b, b, b};
        }
        const unsigned short* pl0 = wll + (size_t)layer * 16384;
        #pragma unroll
        for (int kt = 0; kt < 4; ++kt) {
            const int s = layer * 4 + kt;
            const int p = s & 1;
            #pragma unroll
            for (int ot = 0; ot < 8; ++ot)
                lbl[ot] = ldb(pl0 + (((size_t)(kt * 8 + ot)) * 64 + lane) * 8);
            if (s < 11) {            // prefetch next (layer,kt) bh
                const int nl = (s + 1) >> 2, nk = (s + 1) & 3;
                const unsigned short* ph = wlh + (size_t)nl * 16384;
                #pragma unroll
                for (int ot = 0; ot < 8; ++ot)
                    lbh[p ^ 1][ot] = ldb(ph + (((size_t)(nk * 8 + ot)) * 64 + lane) * 8);
            }
            bf16x8 xh[2], xl[2];
            #pragma unroll
            for (int t = 0; t < 2; ++t) {
                xh[t] = *(const bf16x8*)&XsH[wave][t][col][kt * 32 + kg * 8];
                xl[t] = *(const bf16x8*)&XsL[wave][t][col][kt * 32 + kg * 8];
            }
            #pragma unroll
            for (int ot = 0; ot < 8; ++ot) {
                nacc[0][ot] = MFMA(xh[0], lbh[p][ot], nacc[0][ot]);
                nacc[1][ot] = MFMA(xh[1], lbh[p][ot], nacc[1][ot]);
            }
            #pragma unroll
            for (int ot = 0; ot < 8; ++ot) {
                nacc[0][ot] = MFMA(xl[0], lbh[p][ot], nacc[0][ot]);
                nacc[1][ot] = MFMA(xl[1], lbh[p][ot], nacc[1][ot]);
            }
            #pragma unroll
            for (int ot = 0; ot < 8; ++ot) {
                nacc[0][ot] = MFMA(xh[0], lbl[ot], nacc[0][ot]);
                nacc[1][ot] = MFMA(xh[1], lbl[ot], nacc[1][ot]);
            }
        }
        asm volatile("s_waitcnt lgkmcnt(0)" ::: "memory"); // reads done before overwrite
        #pragma unroll
        for (int t = 0; t < 2; ++t)
            #pragma unroll
            for (int ot = 0; ot < 8; ++ot)
                #pragma unroll
                for (int j = 0; j < 4; ++j) {
                    float x = tanh_fast(nacc[t][ot][j]);
                    unsigned short h, l; split_bf16(x, h, l);
                    XsH[wave][t][kg * 4 + j][col + 16 * ot] = h;
                    XsL[wave][t][kg * 4 + j][col + 16 * ot] = l;
                }
        asm volatile("s_waitcnt lgkmcnt(0)" ::: "memory"); // writes visible to next reads
    }

    // ---- final layer 128 -> 5 (N padded to 16) ----
    float fb = (col < 5) ? bfv[col] : 0.f;
    f32x4 facc[2];
    facc[0] = (f32x4){fb, fb, fb, fb};
    facc[1] = (f32x4){fb, fb, fb, fb};
    #pragma unroll
    for (int kt = 0; kt < 4; ++kt) {
        bf16x8 fh = ldb(wfh + ((size_t)kt * 64 + lane) * 8);
        bf16x8 fl = ldb(wfl + ((size_t)kt * 64 + lane) * 8);
        #pragma unroll
        for (int t = 0; t < 2; ++t) {
            bf16x8 xh = *(const bf16x8*)&XsH[wave][t][col][kt * 32 + kg * 8];
            bf16x8 xl = *(const bf16x8*)&XsL[wave][t][col][kt * 32 + kg * 8];
            facc[t] = MFMA(xh, fh, facc[t]);
            facc[t] = MFMA(xl, fh, facc[t]);
            facc[t] = MFMA(xh, fl, facc[t]);
        }
    }
    if (col < 5) {
        #pragma unroll
        for (int t = 0; t < 2; ++t)
            #pragma unroll
            for (int j = 0; j < 4; ++j) {
                int s = s0 + 16 * t + kg * 4 + j;
                if (s < Btot) out[(size_t)s * 5 + col] = facc[t][j];
            }
    }
}

extern "C" void kernel_launch(void* const* d_in, const int* in_sizes, int n_in,
                              void* d_out, int out_size, void* d_ws, size_t ws_size,
                              hipStream_t stream) {
    const float* data  = (const float*)d_in[0];
    const float* mix_a = (const float*)d_in[1];
    const float* mix_b = (const float*)d_in[2];
    const float* w1    = (const float*)d_in[3];
    const float* b1    = (const float*)d_in[4];
    const float* w2    = (const float*)d_in[5];
    const float* b2    = (const float*)d_in[6];
    const float* w3    = (const float*)d_in[7];
    const float* b3    = (const float*)d_in[8];
    const float* wf    = (const float*)d_in[9];
    const float* bf    = (const float*)d_in[10];
    float* out = (float*)d_out;
    int Btot = in_sizes[0] / 363;

    if (ws_size < 401408) return;   // need 401,408 B of scratch
    unsigned short* wp1h = (unsigned short*)d_ws;      // 49152 ushorts
    unsigned short* wp1l = wp1h + 49152;
    unsigned short* wlh  = wp1l + 49152;               // 3*16384
    unsigned short* wll  = wlh + 49152;
    unsigned short* wfh  = wll + 49152;                // 2048
    unsigned short* wfl  = wfh + 2048;

    prep_all<<<392, 256, 0, stream>>>(mix_a, w1, w2, w3, wf,
                                      wp1h, wp1l, wlh, wll, wfh, wfl);
    int blocks = (Btot + 127) / 128;
    fused_main<<<blocks, 256, 0, stream>>>(data, mix_b, b1, b2, b3, bf,
                                           wp1h, wp1l, wlh, wll, wfh, wfl, out, Btot);
}

// Round 5
// 204.866 us; speedup vs baseline: 1.4092x; 1.0104x over previous
//
#include <hip/hip_runtime.h>
#include <hip/hip_bf16.h>

typedef __attribute__((ext_vector_type(4))) float f32x4;
typedef __attribute__((ext_vector_type(8))) short bf16x8;

#define MFMA(a,b,c) __builtin_amdgcn_mfma_f32_16x16x32_bf16((a),(b),(c),0,0,0)

// Round-to-nearest split of fp32 into hi+lo bf16 (hi = RN(a), lo = RN(a - hi)).
__device__ inline void split_bf16(float a, unsigned short &h, unsigned short &l) {
    unsigned u = __float_as_uint(a);
    unsigned rh = (u + 0x7FFFu + ((u >> 16) & 1u)) & 0xFFFF0000u;
    float hf = __uint_as_float(rh);
    h = (unsigned short)(rh >> 16);
    float lf = a - hf;                      // exact (Sterbenz)
    unsigned u2 = __float_as_uint(lf);
    l = (unsigned short)((u2 + 0x7FFFu + ((u2 >> 16) & 1u)) >> 16);
}

__device__ inline unsigned short bf16_rn(float a) {
    unsigned u = __float_as_uint(a);
    return (unsigned short)((u + 0x7FFFu + ((u >> 16) & 1u)) >> 16);
}

__device__ inline float tanh_fast(float x) {
    float e = __expf(2.f * x);
    return 1.f - 2.f * __builtin_amdgcn_rcpf(e + 1.f);
}

__device__ inline bf16x8 ldb(const unsigned short* p) { return *(const bf16x8*)p; }
// 16B load safe at 4B alignment (memcpy lets the backend pick legal width)
__device__ inline f32x4 ld4u(const float* p) { f32x4 v; __builtin_memcpy(&v, p, 16); return v; }

// ---------------- merged prep: W_eff fold (hi/lo) + layer packs (bf16) ------
// Pack layout (bf16): [ktile][otile][lane][8], lane = (o&15) + 16*((k>>3)&3), j = k&7
__global__ void prep_all(const float* __restrict__ mix_a,
                         const float* __restrict__ w1, const float* __restrict__ w2,
                         const float* __restrict__ w3, const float* __restrict__ wf,
                         unsigned short* __restrict__ wph, unsigned short* __restrict__ wpl,
                         unsigned short* __restrict__ wlh, unsigned short* __restrict__ wfh) {
    int idx = blockIdx.x * 256 + threadIdx.x;
    if (idx < 128 * 384) {
        int o = idx / 384;
        int k = idx - o * 384;
        float acc = 0.f;
        if (k < 363) {
            int c = k / 121, rem = k - c * 121;
            int y = rem / 11, x = rem - y * 11;
            const float* ma = mix_a + (size_t)o * 1215 + c * 81;
            auto add = [&](int f, int i, int j, float coef) {
                int n = y - i, m = x - j;
                if (n >= 0 && n < 9 && m >= 0 && m < 9)
                    acc += ma[f * 243 + n * 9 + m] * coef;
            };
            add(0, 1, 1, 1.f);
            add(1, 0, 1, -5.f);  add(1, 2, 1, 5.f);
            add(2, 1, 0, -5.f);  add(2, 1, 2, 5.f);
            add(3, 0, 1, 100.f); add(3, 1, 1, -200.f); add(3, 2, 1, 100.f);
            add(4, 1, 0, 100.f); add(4, 1, 1, -200.f); add(4, 1, 2, 100.f);
        }
        unsigned short h, l; split_bf16(acc, h, l);
        int kt = k >> 5, ot = o >> 4;
        int lane = (o & 15) + 16 * ((k >> 3) & 3);
        int pidx = ((kt * 8 + ot) * 64 + lane) * 8 + (k & 7);
        wph[pidx] = h; wpl[pidx] = l;
        return;
    }
    idx -= 128 * 384;
    if (idx < 3 * 16384) {
        int layer = idx >> 14; int rem = idx & 16383;
        int o = rem >> 7, k = rem & 127;
        const float* w = (layer == 0) ? w1 : ((layer == 1) ? w2 : w3);
        float v = w[o * 128 + k];
        int kt = k >> 5, ot = o >> 4;
        int lane = (o & 15) + 16 * ((k >> 3) & 3);
        int pidx = layer * 16384 + ((kt * 8 + ot) * 64 + lane) * 8 + (k & 7);
        wlh[pidx] = bf16_rn(v);
    } else if (idx < 3 * 16384 + 2048) {
        int rem = idx - 3 * 16384;
        int o = rem >> 7, k = rem & 127;
        float v = (o < 5) ? wf[o * 128 + k] : 0.f;
        int kt = k >> 5;
        int lane = (o & 15) + 16 * ((k >> 3) & 3);
        int pidx = (kt * 64 + lane) * 8 + (k & 7);
        wfh[pidx] = bf16_rn(v);
    }
}

// ---- fused main: 16 samples/wave, bf16 hidden layers, 4 waves/SIMD target --
__global__ __launch_bounds__(256, 4)
void fused_main(const float* __restrict__ data,
                const float* __restrict__ mix_b,
                const float* __restrict__ b1v,
                const float* __restrict__ b2v,
                const float* __restrict__ b3v,
                const float* __restrict__ bfv,
                const unsigned short* __restrict__ wp1h,
                const unsigned short* __restrict__ wp1l,
                const unsigned short* __restrict__ wlh,
                const unsigned short* __restrict__ wfh,
                float* __restrict__ out, int Btot) {
    __shared__ __align__(16) unsigned short XsH[4][16][136];   // 17,408 B/block

    const int wave = threadIdx.x >> 6;
    const int lane = threadIdx.x & 63;
    const int s0 = (blockIdx.x * 4 + wave) * 16;
    if (s0 >= Btot) return;          // grid exact at B=65536; no barriers used
    const int col = lane & 15;
    const int kg  = lane >> 4;

    const float* arow = data + (size_t)(s0 + col) * 363;

    f32x4 acc[8];
    #pragma unroll
    for (int ot = 0; ot < 8; ++ot) {
        float b = mix_b[col + 16 * ot];
        acc[ot] = (f32x4){b, b, b, b};
    }

    // ---- stage 1: mixed = data @ W_eff^T (hi/lo 3-pass), 12 k-steps of 32 --
    bf16x8 bh[8];
    f32x4 a4[2][2];                   // [ping-pong][half-of-8-floats]
    a4[0][0] = ld4u(arow + kg * 8);
    a4[0][1] = ld4u(arow + kg * 8 + 4);

    #pragma unroll
    for (int ktg = 0; ktg < 12; ++ktg) {
        const int p = ktg & 1;
        #pragma unroll
        for (int ot = 0; ot < 8; ++ot)
            bh[ot] = ldb(wp1h + (((size_t)(ktg * 8 + ot)) * 64 + lane) * 8);
        // prefetch next step's A (HBM)
        if (ktg < 10) {
            const int kb = (ktg + 1) * 32 + kg * 8;
            a4[p ^ 1][0] = ld4u(arow + kb);
            a4[p ^ 1][1] = ld4u(arow + kb + 4);
        } else if (ktg == 10) {
            // last k-step: masked scalar (don't run past row end at k>=363)
            #pragma unroll
            for (int i = 0; i < 2; ++i)
                #pragma unroll
                for (int j = 0; j < 4; ++j) {
                    int k = 352 + kg * 8 + i * 4 + j;
                    bool ok = (k < 363);
                    a4[p ^ 1][i][j] = ok ? arow[k] : 0.f;
                }
        }
        // split current A into hi/lo fragments
        bf16x8 ah, al;
        #pragma unroll
        for (int i = 0; i < 2; ++i)
            #pragma unroll
            for (int j = 0; j < 4; ++j) {
                unsigned short hh, ll;
                split_bf16(a4[p][i][j], hh, ll);
                ah[i * 4 + j] = (short)hh;
                al[i * 4 + j] = (short)ll;
            }
        #pragma unroll
        for (int ot = 0; ot < 8; ++ot)
            acc[ot] = MFMA(ah, bh[ot], acc[ot]);
        #pragma unroll
        for (int ot = 0; ot < 8; ++ot)
            acc[ot] = MFMA(al, bh[ot], acc[ot]);
        #pragma unroll
        for (int ot = 0; ot < 8; ++ot) {   // bl inlined: low live range
            bf16x8 bl = ldb(wp1l + (((size_t)(ktg * 8 + ot)) * 64 + lane) * 8);
            acc[ot] = MFMA(ah, bl, acc[ot]);
        }
    }

    // preload layer-0 kt-0 B fragments (overlaps with tanh VALU below)
    bf16x8 lbh[2][8];
    #pragma unroll
    for (int ot = 0; ot < 8; ++ot)
        lbh[0][ot] = ldb(wlh + ((size_t)ot * 64 + lane) * 8);

    // mixed -> tanh -> Xs (bf16 only; saturated values are exact in bf16)
    #pragma unroll
    for (int ot = 0; ot < 8; ++ot)
        #pragma unroll
        for (int j = 0; j < 4; ++j)
            XsH[wave][kg * 4 + j][col + 16 * ot] = bf16_rn(tanh_fast(acc[ot][j]));

    // ---- 3 hidden layers (bf16 x bf16), flattened 12 k-steps, bh dbuf ----
    const float* biases[3] = {b1v, b2v, b3v};
    asm volatile("s_waitcnt lgkmcnt(0)" ::: "memory");   // X writes visible (in-wave)

    #pragma unroll
    for (int layer = 0; layer < 3; ++layer) {
        const float* bb = biases[layer];
        f32x4 nacc[8];
        #pragma unroll
        for (int ot = 0; ot < 8; ++ot) {
            float b = bb[col + 16 * ot];
            nacc[ot] = (f32x4){b, b, b, b};
        }
        #pragma unroll
        for (int kt = 0; kt < 4; ++kt) {
            const int s = layer * 4 + kt;
            const int p = s & 1;
            if (s < 11) {            // prefetch next (layer,kt) B
                const int nl = (s + 1) >> 2, nk = (s + 1) & 3;
                const unsigned short* ph = wlh + (size_t)nl * 16384;
                #pragma unroll
                for (int ot = 0; ot < 8; ++ot)
                    lbh[p ^ 1][ot] = ldb(ph + (((size_t)(nk * 8 + ot)) * 64 + lane) * 8);
            }
            bf16x8 xh = *(const bf16x8*)&XsH[wave][col][kt * 32 + kg * 8];
            #pragma unroll
            for (int ot = 0; ot < 8; ++ot)
                nacc[ot] = MFMA(xh, lbh[p][ot], nacc[ot]);
        }
        asm volatile("s_waitcnt lgkmcnt(0)" ::: "memory"); // X reads done before overwrite
        #pragma unroll
        for (int ot = 0; ot < 8; ++ot)
            #pragma unroll
            for (int j = 0; j < 4; ++j)
                XsH[wave][kg * 4 + j][col + 16 * ot] = bf16_rn(tanh_fast(nacc[ot][j]));
        asm volatile("s_waitcnt lgkmcnt(0)" ::: "memory"); // writes visible to next reads
    }

    // ---- final layer 128 -> 5 (N padded to 16), bf16 ----
    float fb = (col < 5) ? bfv[col] : 0.f;
    f32x4 facc = (f32x4){fb, fb, fb, fb};
    #pragma unroll
    for (int kt = 0; kt < 4; ++kt) {
        bf16x8 fh = ldb(wfh + ((size_t)kt * 64 + lane) * 8);
        bf16x8 xh = *(const bf16x8*)&XsH[wave][col][kt * 32 + kg * 8];
        facc = MFMA(xh, fh, facc);
    }
    if (col < 5) {
        #pragma unroll
        for (int j = 0; j < 4; ++j) {
            int s = s0 + kg * 4 + j;
            if (s < Btot) out[(size_t)s * 5 + col] = facc[j];
        }
    }
}

extern "C" void kernel_launch(void* const* d_in, const int* in_sizes, int n_in,
                              void* d_out, int out_size, void* d_ws, size_t ws_size,
                              hipStream_t stream) {
    const float* data  = (const float*)d_in[0];
    const float* mix_a = (const float*)d_in[1];
    const float* mix_b = (const float*)d_in[2];
    const float* w1    = (const float*)d_in[3];
    const float* b1    = (const float*)d_in[4];
    const float* w2    = (const float*)d_in[5];
    const float* b2    = (const float*)d_in[6];
    const float* w3    = (const float*)d_in[7];
    const float* b3    = (const float*)d_in[8];
    const float* wf    = (const float*)d_in[9];
    const float* bf    = (const float*)d_in[10];
    float* out = (float*)d_out;
    int Btot = in_sizes[0] / 363;

    if (ws_size < 299008) return;   // wp1h+wp1l+wlh+wfh = 149,504 ushorts
    unsigned short* wp1h = (unsigned short*)d_ws;      // 49152 ushorts
    unsigned short* wp1l = wp1h + 49152;               // 49152
    unsigned short* wlh  = wp1l + 49152;               // 3*16384
    unsigned short* wfh  = wlh + 49152;                // 2048

    prep_all<<<392, 256, 0, stream>>>(mix_a, w1, w2, w3, wf,
                                      wp1h, wp1l, wlh, wfh);
    int blocks = (Btot + 63) / 64;
    fused_main<<<blocks, 256, 0, stream>>>(data, mix_b, b1, b2, b3, bf,
                                           wp1h, wp1l, wlh, wfh, out, Btot);
}

// Round 7
// 185.973 us; speedup vs baseline: 1.5523x; 1.1016x over previous
//
#include <hip/hip_runtime.h>
#include <hip/hip_bf16.h>

typedef __attribute__((ext_vector_type(4))) float f32x4;
typedef __attribute__((ext_vector_type(8))) short bf16x8;

#define MFMA(a,b,c) __builtin_amdgcn_mfma_f32_16x16x32_bf16((a),(b),(c),0,0,0)

// Round-to-nearest split of fp32 into hi+lo bf16 (hi = RN(a), lo = RN(a - hi)).
__device__ inline void split_bf16(float a, unsigned short &h, unsigned short &l) {
    unsigned u = __float_as_uint(a);
    unsigned rh = (u + 0x7FFFu + ((u >> 16) & 1u)) & 0xFFFF0000u;
    float hf = __uint_as_float(rh);
    h = (unsigned short)(rh >> 16);
    float lf = a - hf;                      // exact (Sterbenz)
    unsigned u2 = __float_as_uint(lf);
    l = (unsigned short)((u2 + 0x7FFFu + ((u2 >> 16) & 1u)) >> 16);
}

__device__ inline unsigned short bf16_rn(float a) {
    unsigned u = __float_as_uint(a);
    return (unsigned short)((u + 0x7FFFu + ((u >> 16) & 1u)) >> 16);
}

__device__ inline float tanh_fast(float x) {
    float e = __expf(2.f * x);
    return 1.f - 2.f * __builtin_amdgcn_rcpf(e + 1.f);
}

__device__ inline bf16x8 ldb(const unsigned short* p) { return *(const bf16x8*)p; }
// 16B load safe at 4B alignment (memcpy lets the backend pick legal width)
__device__ inline f32x4 ld4u(const float* p) { f32x4 v; __builtin_memcpy(&v, p, 16); return v; }

// ---------------- merged prep: W_eff fold (hi/lo) + layer packs (bf16) ------
// Pack layout (bf16): [ktile][otile][lane][8], lane = (o&15) + 16*((k>>3)&3), j = k&7
__global__ void prep_all(const float* __restrict__ mix_a,
                         const float* __restrict__ w1, const float* __restrict__ w2,
                         const float* __restrict__ w3, const float* __restrict__ wf,
                         unsigned short* __restrict__ wph, unsigned short* __restrict__ wpl,
                         unsigned short* __restrict__ wlh, unsigned short* __restrict__ wfh) {
    int idx = blockIdx.x * 256 + threadIdx.x;
    if (idx < 128 * 384) {
        int o = idx / 384;
        int k = idx - o * 384;
        float acc = 0.f;
        if (k < 363) {
            int c = k / 121, rem = k - c * 121;
            int y = rem / 11, x = rem - y * 11;
            const float* ma = mix_a + (size_t)o * 1215 + c * 81;
            auto add = [&](int f, int i, int j, float coef) {
                int n = y - i, m = x - j;
                if (n >= 0 && n < 9 && m >= 0 && m < 9)
                    acc += ma[f * 243 + n * 9 + m] * coef;
            };
            add(0, 1, 1, 1.f);
            add(1, 0, 1, -5.f);  add(1, 2, 1, 5.f);
            add(2, 1, 0, -5.f);  add(2, 1, 2, 5.f);
            add(3, 0, 1, 100.f); add(3, 1, 1, -200.f); add(3, 2, 1, 100.f);
            add(4, 1, 0, 100.f); add(4, 1, 1, -200.f); add(4, 1, 2, 100.f);
        }
        unsigned short h, l; split_bf16(acc, h, l);
        int kt = k >> 5, ot = o >> 4;
        int lane = (o & 15) + 16 * ((k >> 3) & 3);
        int pidx = ((kt * 8 + ot) * 64 + lane) * 8 + (k & 7);
        wph[pidx] = h; wpl[pidx] = l;
        return;
    }
    idx -= 128 * 384;
    if (idx < 3 * 16384) {
        int layer = idx >> 14; int rem = idx & 16383;
        int o = rem >> 7, k = rem & 127;
        const float* w = (layer == 0) ? w1 : ((layer == 1) ? w2 : w3);
        float v = w[o * 128 + k];
        int kt = k >> 5, ot = o >> 4;
        int lane = (o & 15) + 16 * ((k >> 3) & 3);
        int pidx = layer * 16384 + ((kt * 8 + ot) * 64 + lane) * 8 + (k & 7);
        wlh[pidx] = bf16_rn(v);
    } else if (idx < 3 * 16384 + 2048) {
        int rem = idx - 3 * 16384;
        int o = rem >> 7, k = rem & 127;
        float v = (o < 5) ? wf[o * 128 + k] : 0.f;
        int kt = k >> 5;
        int lane = (o & 15) + 16 * ((k >> 3) & 3);
        int pidx = (kt * 64 + lane) * 8 + (k & 7);
        wfh[pidx] = bf16_rn(v);
    }
}

// ---- fused main: block-shared B via LDS, T14 staging, 4 blocks/CU ----------
__global__ __launch_bounds__(256, 4)
void fused_main(const float* __restrict__ data,
                const float* __restrict__ mix_b,
                const float* __restrict__ b1v,
                const float* __restrict__ b2v,
                const float* __restrict__ b3v,
                const float* __restrict__ bfv,
                const unsigned short* __restrict__ wp1h,
                const unsigned short* __restrict__ wp1l,
                const unsigned short* __restrict__ wlh,
                const unsigned short* __restrict__ wfh,
                float* __restrict__ out, int Btot) {
    __shared__ __align__(16) unsigned short BstH[4096];        // 8 KB B-slice (hi)
    __shared__ __align__(16) unsigned short BstL[4096];        // 8 KB B-slice (lo)
    __shared__ __align__(16) unsigned short XsH[4][16][136];   // 17,408 B

    const int t    = threadIdx.x;
    const int wave = t >> 6;
    const int lane = t & 63;
    const int col  = lane & 15;
    const int kg   = lane >> 4;
    const int s0   = blockIdx.x * 64 + wave * 16;

    int arowi = s0 + col;
    if (arowi >= Btot) arowi = (Btot > 0) ? (Btot - 1) : 0;   // clamp loads; stores masked
    const float* arow = data + (size_t)arowi * 363;

    // ---- initial: stage S0 into LDS (hi+lo), start A load ----
    {
        bf16x8 h0 = ldb(wp1h + t * 8);
        bf16x8 h1 = ldb(wp1h + 2048 + t * 8);
        bf16x8 l0 = ldb(wp1l + t * 8);
        bf16x8 l1 = ldb(wp1l + 2048 + t * 8);
        *(bf16x8*)&BstH[t * 8] = h0;  *(bf16x8*)&BstH[2048 + t * 8] = h1;
        *(bf16x8*)&BstL[t * 8] = l0;  *(bf16x8*)&BstL[2048 + t * 8] = l1;
    }
    f32x4 acc[8];
    #pragma unroll
    for (int ot = 0; ot < 8; ++ot) {
        float b = mix_b[col + 16 * ot];
        acc[ot] = (f32x4){b, b, b, b};
    }
    f32x4 a4[2][2];
    a4[0][0] = ld4u(arow + kg * 8);
    a4[0][1] = ld4u(arow + kg * 8 + 4);
    __syncthreads();

    // ---- stage 1: mixed = data @ W_eff^T (hi/lo 3-pass), 12 k-steps of 32 --
    bf16x8 pre0, pre1, pre2, pre3;
    #pragma unroll
    for (int ktg = 0; ktg < 12; ++ktg) {
        const int p = ktg & 1;
        // prefetch next B slice (global -> regs; hides under MFMA below)
        if (ktg < 11) {
            const unsigned short* nh = wp1h + (size_t)(ktg + 1) * 4096;
            const unsigned short* nl = wp1l + (size_t)(ktg + 1) * 4096;
            pre0 = ldb(nh + t * 8); pre1 = ldb(nh + 2048 + t * 8);
            pre2 = ldb(nl + t * 8); pre3 = ldb(nl + 2048 + t * 8);
        } else {   // next up: layer0/kt0 slice (hi only)
            pre0 = ldb(wlh + t * 8); pre1 = ldb(wlh + 2048 + t * 8);
        }
        // prefetch next A chunk
        if (ktg < 10) {
            const int kb = (ktg + 1) * 32 + kg * 8;
            a4[p ^ 1][0] = ld4u(arow + kb);
            a4[p ^ 1][1] = ld4u(arow + kb + 4);
        } else if (ktg == 10) {
            #pragma unroll
            for (int i = 0; i < 2; ++i)
                #pragma unroll
                for (int j = 0; j < 4; ++j) {
                    int k = 352 + kg * 8 + i * 4 + j;
                    bool ok = (k < 363);
                    a4[p ^ 1][i][j] = ok ? arow[k] : 0.f;
                }
        }
        // split current A into hi/lo
        bf16x8 ah, al;
        #pragma unroll
        for (int i = 0; i < 2; ++i)
            #pragma unroll
            for (int j = 0; j < 4; ++j) {
                unsigned short hh, ll;
                split_bf16(a4[p][i][j], hh, ll);
                ah[i * 4 + j] = (short)hh;
                al[i * 4 + j] = (short)ll;
            }
        // fragments from LDS + MFMA (bh reused for 2 passes while live)
        #pragma unroll
        for (int ot = 0; ot < 8; ++ot) {
            bf16x8 bh = *(const bf16x8*)&BstH[(ot * 64 + lane) * 8];
            acc[ot] = MFMA(ah, bh, acc[ot]);
            acc[ot] = MFMA(al, bh, acc[ot]);
        }
        #pragma unroll
        for (int ot = 0; ot < 8; ++ot) {
            bf16x8 bl = *(const bf16x8*)&BstL[(ot * 64 + lane) * 8];
            acc[ot] = MFMA(ah, bl, acc[ot]);
        }
        if (ktg == 11) {   // mixed -> tanh -> Xs (VALU, overlaps barrier wait)
            #pragma unroll
            for (int ot = 0; ot < 8; ++ot)
                #pragma unroll
                for (int j = 0; j < 4; ++j)
                    XsH[wave][kg * 4 + j][col + 16 * ot] = bf16_rn(tanh_fast(acc[ot][j]));
        }
        __syncthreads();                       // all waves done reading Bst
        *(bf16x8*)&BstH[t * 8] = pre0;
        *(bf16x8*)&BstH[2048 + t * 8] = pre1;
        if (ktg < 11) {
            *(bf16x8*)&BstL[t * 8] = pre2;
            *(bf16x8*)&BstL[2048 + t * 8] = pre3;
        }
        __syncthreads();                       // staged slice visible
    }

    // ---- 3 hidden layers (bf16 x bf16), Bst holds slice s = layer*4+kt ----
    const float* biases[3] = {b1v, b2v, b3v};
    #pragma unroll
    for (int layer = 0; layer < 3; ++layer) {
        const float* bb = biases[layer];
        f32x4 nacc[8];
        #pragma unroll
        for (int ot = 0; ot < 8; ++ot) {
            float b = bb[col + 16 * ot];
            nacc[ot] = (f32x4){b, b, b, b};
        }
        #pragma unroll
        for (int kt = 0; kt < 4; ++kt) {
            const int s = layer * 4 + kt;
            if (s < 11) {                      // prefetch next layer slice
                const unsigned short* nsl = wlh + (size_t)(s + 1) * 4096;
                pre0 = ldb(nsl + t * 8); pre1 = ldb(nsl + 2048 + t * 8);
            } else {                           // prefetch final-layer slice (2048 ushorts)
                pre0 = ldb(wfh + t * 8);
            }
            bf16x8 xh = *(const bf16x8*)&XsH[wave][col][kt * 32 + kg * 8];
            #pragma unroll
            for (int ot = 0; ot < 8; ++ot) {
                bf16x8 bh = *(const bf16x8*)&BstH[(ot * 64 + lane) * 8];
                nacc[ot] = MFMA(xh, bh, nacc[ot]);
            }
            __syncthreads();                   // reads done
            *(bf16x8*)&BstH[t * 8] = pre0;
            if (s < 11) *(bf16x8*)&BstH[2048 + t * 8] = pre1;
            __syncthreads();                   // writes visible
        }
        #pragma unroll
        for (int ot = 0; ot < 8; ++ot)
            #pragma unroll
            for (int j = 0; j < 4; ++j)
                XsH[wave][kg * 4 + j][col + 16 * ot] = bf16_rn(tanh_fast(nacc[ot][j]));
        asm volatile("s_waitcnt lgkmcnt(0)" ::: "memory");   // in-wave X visibility
    }

    // ---- final layer 128 -> 5 (N padded to 16); Bst holds wfh slice ----
    float fb = (col < 5) ? bfv[col] : 0.f;
    f32x4 facc = (f32x4){fb, fb, fb, fb};
    #pragma unroll
    for (int kt = 0; kt < 4; ++kt) {
        bf16x8 fh = *(const bf16x8*)&BstH[(kt * 64 + lane) * 8];
        bf16x8 xh = *(const bf16x8*)&XsH[wave][col][kt * 32 + kg * 8];
        facc = MFMA(xh, fh, facc);
    }
    if (col < 5) {
        #pragma unroll
        for (int j = 0; j < 4; ++j) {
            int s = s0 + kg * 4 + j;
            if (s < Btot) out[(size_t)s * 5 + col] = facc[j];
        }
    }
}

extern "C" void kernel_launch(void* const* d_in, const int* in_sizes, int n_in,
                              void* d_out, int out_size, void* d_ws, size_t ws_size,
                              hipStream_t stream) {
    const float* data  = (const float*)d_in[0];
    const float* mix_a = (const float*)d_in[1];
    const float* mix_b = (const float*)d_in[2];
    const float* w1    = (const float*)d_in[3];
    const float* b1    = (const float*)d_in[4];
    const float* w2    = (const float*)d_in[5];
    const float* b2    = (const float*)d_in[6];
    const float* w3    = (const float*)d_in[7];
    const float* b3    = (const float*)d_in[8];
    const float* wf    = (const float*)d_in[9];
    const float* bf    = (const float*)d_in[10];
    float* out = (float*)d_out;
    int Btot = in_sizes[0] / 363;

    if (ws_size < 299008) return;   // wp1h+wp1l+wlh+wfh = 149,504 ushorts
    unsigned short* wp1h = (unsigned short*)d_ws;      // 49152 ushorts
    unsigned short* wp1l = wp1h + 49152;               // 49152
    unsigned short* wlh  = wp1l + 49152;               // 3*16384
    unsigned short* wfh  = wlh + 49152;                // 2048

    prep_all<<<392, 256, 0, stream>>>(mix_a, w1, w2, w3, wf,
                                      wp1h, wp1l, wlh, wfh);
    int blocks = (Btot + 63) / 64;
    fused_main<<<blocks, 256, 0, stream>>>(data, mix_b, b1, b2, b3, bf,
                                           wp1h, wp1l, wlh, wfh, out, Btot);
}